// Round 1
// baseline (145.732 us; speedup 1.0000x reference)
//
#include <hip/hip_runtime.h>
#include <math.h>

// Problem constants: B=32, C=D=64, H=W=32
#define NPTS 32768      // B*H*W
#define KCB  1024
#define DIM  64
#define HW   1024
#define CHW  65536

typedef short  bf16x8 __attribute__((ext_vector_type(8)));
typedef float  f32x16 __attribute__((ext_vector_type(16)));

__device__ __forceinline__ unsigned short f2b_rne(float f) {
  unsigned u = __float_as_uint(f);
  unsigned r = 0x7FFFu + ((u >> 16) & 1u);
  return (unsigned short)((u + r) >> 16);
}

__device__ __forceinline__ float block_sum(float v, float* scratch) {
  #pragma unroll
  for (int o = 32; o > 0; o >>= 1) v += __shfl_down(v, o, 64);
  int wid  = threadIdx.x >> 6;
  int lane = threadIdx.x & 63;
  __syncthreads();
  if (lane == 0) scratch[wid] = v;
  __syncthreads();
  float s = 0.f;
  int nw = blockDim.x >> 6;
  for (int w = 0; w < nw; ++w) s += scratch[w];
  return s;
}

// K0: codebook -> fragment-ordered bf16 hi/lo global array + cnorm (exact chain).
// Also zeroes hist (1024 threads cover 1024 bins) -> memset dispatch removed.
__global__ __launch_bounds__(64) void k_cvt(const float* __restrict__ cb,
                                            float4* __restrict__ cbf,
                                            float* __restrict__ cnorm,
                                            int* __restrict__ hist) {
  int c = blockIdx.x * 64 + threadIdx.x;   // 16 blocks x 64 = 1024 codes
  hist[c] = 0;
  const float4* row4 = (const float4*)(cb + c * DIM);
  float4 r[16];
  #pragma unroll
  for (int i = 0; i < 16; ++i) r[i] = row4[i];
  float s = 0.f;
  #pragma unroll
  for (int i = 0; i < 16; ++i) {          // exact f4 fmaf chain (validated rounds)
    s = fmaf(r[i].x, r[i].x, s); s = fmaf(r[i].y, r[i].y, s);
    s = fmaf(r[i].z, r[i].z, s); s = fmaf(r[i].w, r[i].w, s);
  }
  cnorm[c] = s;
  int ch = c >> 6, nt = (c >> 5) & 1, n = c & 31;
  int base = ch * 1024 + nt * 256 + n;
  #pragma unroll
  for (int o = 0; o < 8; ++o) {           // octet o = dims 8o..8o+7
    float f[8] = {r[2*o].x, r[2*o].y, r[2*o].z, r[2*o].w,
                  r[2*o+1].x, r[2*o+1].y, r[2*o+1].z, r[2*o+1].w};
    unsigned hu[4], lu[4];
    #pragma unroll
    for (int j = 0; j < 4; ++j) {
      unsigned short h0 = f2b_rne(f[2*j]),   h1 = f2b_rne(f[2*j+1]);
      float hf0 = __uint_as_float((unsigned)h0 << 16);
      float hf1 = __uint_as_float((unsigned)h1 << 16);
      unsigned short l0 = f2b_rne(f[2*j] - hf0), l1 = f2b_rne(f[2*j+1] - hf1);
      hu[j] = (unsigned)h0 | ((unsigned)h1 << 16);
      lu[j] = (unsigned)l0 | ((unsigned)l1 << 16);
    }
    int pos = base + (o >> 1) * 64 + (o & 1) * 32;   // s = o>>1, u = o&1
    uint4 hv = {hu[0], hu[1], hu[2], hu[3]};
    uint4 lv = {lu[0], lu[1], lu[2], lu[3]};
    cbf[pos]       = *(float4*)&hv;
    cbf[pos + 512] = *(float4*)&lv;
  }
}

// K1: 32x32x16-MFMA distance GEMM + fused fin. 512 blocks x 64 pts, all codes.
// NEW: 512 threads / 8 waves per block. Wave (h, wm, wn): h = code-half
// (chunks h*8..h*8+7 walked concurrently), wm = m-tile, wn = n-half of chunk.
// -> 16 waves/CU (was 8): the two halves that were serial chunks 8..15 now
// run as independent wave streams, halving the per-block serial chain.
// Per-chunk math (frag order, 12-MFMA chain, dist formula, first-min scan,
// packed-u64 ties) is verbatim from the validated kernel -> bit-exact.
// LDS: points (lph/lpl) overlay the 32KB code buffer (points LDS is dead
// after A-frags land in registers) -> 40.5 KB total.
__global__ __launch_bounds__(512, 4) void k_dist(const float* __restrict__ x,
                                                 const float* __restrict__ cb,
                                                 const float4* __restrict__ cbf,
                                                 const float* __restrict__ cnorm,
                                                 int* __restrict__ hist,
                                                 float* __restrict__ msep,
                                                 float* __restrict__ out) {
  // 32 KB region: bbuf[2 halves][8192 shorts]  UNION  (lph[64][72] | lpl[64][72])
  __shared__ __align__(16) short s_big[16384];
  __shared__ float s_cn[KCB];
  __shared__ float s_sx[64], s_part[4][64];
  __shared__ unsigned long long s_pk[64][4];
  __shared__ int   s_bd[64];
  __shared__ float scratch[8];

  unsigned short (*lph)[72] = (unsigned short (*)[72])&s_big[0];     // 9216 B
  unsigned short (*lpl)[72] = (unsigned short (*)[72])&s_big[4608];  // 9216 B

  int tid = threadIdx.x;
  int t   = blockIdx.x;
  int n0  = t * 64;
  int b   = n0 >> 10;
  int hw0 = n0 & 1023;

  int hh = tid >> 8, r2 = tid & 255;   // staging role: half hh, slot r2

  // prefetch iteration-0 chunk pair (all 512 threads, 64 B each, linear)
  float4 pf[4];
  #pragma unroll
  for (int j = 0; j < 4; ++j) pf[j] = cbf[hh * 8192 + r2 + 256 * j];

  // point staging + bf16 hi/lo conversion: tid<256 only, exact q4-chain
  // layout preserved from the validated kernel (bitwise-identical s_sx).
  // fx[] keeps the exact x values in registers for the fused fin (no re-read).
  float fx[16];
  if (tid < 256) {
    *(float4*)&s_cn[tid * 4] = *(const float4*)(cnorm + tid * 4);
    int p = tid & 63, q4 = tid >> 6;
    const float* xb = x + b * CHW + hw0 + p;
    float s = 0.f;
    unsigned short hb[16], lb[16];
    #pragma unroll
    for (int i = 0; i < 16; ++i) {
      int c = q4 * 16 + i;
      float f = xb[c * HW];
      fx[i] = f;
      s = fmaf(f, f, s);
      unsigned short hsh = f2b_rne(f);
      float hf = __uint_as_float(((unsigned)hsh) << 16);
      hb[i] = hsh;
      lb[i] = f2b_rne(f - hf);
    }
    s_part[q4][p] = s;
    #pragma unroll
    for (int j = 0; j < 8; ++j) {
      *(unsigned*)&lph[p][q4 * 16 + 2 * j] = (unsigned)hb[2*j] | ((unsigned)hb[2*j+1] << 16);
      *(unsigned*)&lpl[p][q4 * 16 + 2 * j] = (unsigned)lb[2*j] | ((unsigned)lb[2*j+1] << 16);
    }
  }
  // lgkm-only barriers: prologue pf loads stay in flight
  __builtin_amdgcn_s_waitcnt(0xc07f);
  __builtin_amdgcn_s_barrier();
  if (tid < 64)
    s_sx[tid] = ((s_part[0][tid] + s_part[1][tid]) + s_part[2][tid]) + s_part[3][tid];
  __builtin_amdgcn_s_waitcnt(0xc07f);
  __builtin_amdgcn_s_barrier();

  int w = tid >> 6, l = tid & 63;
  int h = w >> 2, wm = (w >> 1) & 1, wn = w & 1;
  int u = l >> 5, n = l & 31;

  // A-frags: lane holds A[m=n][k=u*8+j] for k-step s -> octet (2s+u) of point row
  bf16x8 ah[4], al[4];
  {
    int pt = wm * 32 + n;
    #pragma unroll
    for (int s = 0; s < 4; ++s) {
      ah[s] = *(const bf16x8*)&lph[pt][(2 * s + u) * 8];
      al[s] = *(const bf16x8*)&lpl[pt][(2 * s + u) * 8];
    }
  }
  // C/D 32x32 layout: col=lane&31, row=(reg&3)+8*(reg>>2)+4*(lane>>5)  [m74/m101]
  float sxr[16];
  #pragma unroll
  for (int r = 0; r < 16; ++r)
    sxr[r] = s_sx[wm * 32 + (r & 3) + 8 * (r >> 2) + 4 * u];

  float best[16]; int bidx[16];
  #pragma unroll
  for (int r = 0; r < 16; ++r) { best[r] = 3.4e38f; bidx[r] = 0; }

  int bofs = wn * 256 + u * 32 + n;          // f4 base for s=0 hi frag
  const short* bbr = &s_big[h  * 8192];      // this wave reads half h
  short*       bbw = &s_big[hh * 8192];      // this thread writes half hh

  for (int i = 0; i < 8; ++i) {
    // barrier1: all prior s_big reads drained (A-frags at i==0, B-frags after)
    __builtin_amdgcn_s_waitcnt(0xc07f);
    __builtin_amdgcn_s_barrier();
    __builtin_amdgcn_sched_barrier(0);       // don't hoist writes above barrier
    #pragma unroll
    for (int j = 0; j < 4; ++j)              // linear store, conflict-free
      *(float4*)&bbw[(r2 + 256 * j) * 8] = pf[j];
    if (i < 7) {
      #pragma unroll
      for (int j = 0; j < 4; ++j)
        pf[j] = cbf[(hh * 8 + i + 1) * 1024 + r2 + 256 * j];
    }
    __builtin_amdgcn_s_waitcnt(0xc07f);      // ds_writes visible; pf in flight
    __builtin_amdgcn_s_barrier();
    __builtin_amdgcn_sched_barrier(0);

    f32x16 acc;
    #pragma unroll
    for (int r = 0; r < 16; ++r) acc[r] = 0.f;
    #pragma unroll
    for (int s = 0; s < 4; ++s) {
      bf16x8 bh = *(const bf16x8*)&bbr[(bofs + s * 64) * 8];
      bf16x8 bl = *(const bf16x8*)&bbr[(bofs + s * 64 + 512) * 8];
      acc = __builtin_amdgcn_mfma_f32_32x32x16_bf16(ah[s], bh, acc, 0, 0, 0);
      acc = __builtin_amdgcn_mfma_f32_32x32x16_bf16(ah[s], bl, acc, 0, 0, 0);
      acc = __builtin_amdgcn_mfma_f32_32x32x16_bf16(al[s], bh, acc, 0, 0, 0);
    }
    int   kk  = (h * 8 + i) * 64 + wn * 32 + n;
    float cnv = s_cn[kk];
    #pragma unroll
    for (int r = 0; r < 16; ++r) {
      // reference fp32 rounding shape: (||x||^2 + ||c||^2) - 2*x.c
      float dist = (sxr[r] + cnv) - 2.0f * acc[r];
      if (dist < best[r]) { best[r] = dist; bidx[r] = kk; }  // asc kk -> first-min
    }
  }

  // cross-lane argmin within each 32-lane half (cols of the 32x32 tile)
  #pragma unroll
  for (int r = 0; r < 16; ++r) {
    unsigned long long p =
        ((unsigned long long)__float_as_uint(best[r]) << 32) | (unsigned)bidx[r];
    #pragma unroll
    for (int m = 1; m < 32; m <<= 1) {
      unsigned long long o = __shfl_xor(p, m, 64);
      p = (o < p) ? o : p;
    }
    if (n == 0)
      s_pk[wm * 32 + (r & 3) + 8 * (r >> 2) + 4 * u][h * 2 + wn] = p;
  }
  __syncthreads();
  if (tid < 64) {
    unsigned long long m0 = s_pk[tid][0], m1 = s_pk[tid][1];
    unsigned long long m2 = s_pk[tid][2], m3 = s_pk[tid][3];
    unsigned long long a  = (m1 < m0) ? m1 : m0;   // packed: tie -> lower idx
    unsigned long long c2 = (m3 < m2) ? m3 : m2;
    unsigned long long mn = (c2 < a) ? c2 : a;
    int bd = (int)(mn & 0xffffffffull);
    s_bd[tid] = bd;
    atomicAdd(&hist[bd], 1);
  }
  __syncthreads();

  // fused fin: gather code row, straight-through write (ref rounding), mse.
  // tid<256 with x from registers (fx) -> exact same per-thread se chain.
  float se = 0.f;
  if (tid < 256) {
    int p = tid & 63, cg = tid >> 6;
    int bd = s_bd[p];
    const float* crow = cb + bd * DIM;
    float* ob = out + b * CHW + hw0 + p;
    #pragma unroll 4
    for (int i = 0; i < 16; ++i) {
      int c = cg * 16 + i;
      float xv   = fx[i];              // exact x (kept in regs from staging)
      float diff = crow[c] - xv;       // nq - x
      se += diff * diff;               // (clean_q - flat)^2 == commit mse
      ob[c * HW] = xv + diff;          // x + stop_grad(nq - x)
    }
  }
  float tot = block_sum(se, scratch);  // waves 4..7 add exact +0.0
  if (tid == 0) msep[t] = tot;         // plain store: no atomics, no pre-zero
}

// K2: prep + banded OT dual ascent + scalars (R8 structure, unchanged).
__global__ __launch_bounds__(256) void k_ot(const int* __restrict__ hist,
                                            const float* __restrict__ msep,
                                            float* __restrict__ out) {
  __shared__ __align__(16) float s_lt[KCB + 8], s_src[KCB + 8],
                                 s_phi[KCB + 8], s_lse[KCB + 8];
  __shared__ float scratch[4];
  int tid = threadIdx.x;
  int i0  = tid * 4;
  int sl0 = i0 + 4;

  float msetot = block_sum(msep[tid] + msep[tid + 256], scratch);

  int4 hi4 = *(const int4*)(hist + i0);
  int  hi[4] = {hi4.x, hi4.y, hi4.z, hi4.w};
  float tj[4], hj[4];
  #pragma unroll
  for (int j = 0; j < 4; ++j) {
    float fi = (float)(i0 + j);
    float zz = (fi - 511.5f) / (1024.0f / 6.0f);
    tj[j] = expf(-0.5f * zz * zz);
    hj[j] = (float)hi[j] * (1.0f / 32768.0f);
  }
  float St = block_sum(tj[0] + tj[1] + tj[2] + tj[3], scratch);
  float tgt[4], ltw[4];
  float l2 = 0.f;
  #pragma unroll
  for (int j = 0; j < 4; ++j) { tgt[j] = fmaxf(tj[j] / fmaxf(St, 1e-12f), 1e-12f); l2 += tgt[j]; }
  float St2 = block_sum(l2, scratch);
  #pragma unroll
  for (int j = 0; j < 4; ++j) { tgt[j] = tgt[j] / St2; ltw[j] = logf(fmaxf(tgt[j], 1e-12f)); }

  float m1[4], srcw[4];
  float l3 = 0.f;
  #pragma unroll
  for (int j = 0; j < 4; ++j) { m1[j] = fmaxf(hj[j], 1e-12f); l3 += m1[j]; }
  float S1 = block_sum(l3, scratch);
  float l4 = 0.f;
  #pragma unroll
  for (int j = 0; j < 4; ++j) { srcw[j] = fmaxf(m1[j] / S1, 1e-12f); l4 += srcw[j]; }
  float S2 = block_sum(l4, scratch);
  float l5 = 0.f;
  #pragma unroll
  for (int j = 0; j < 4; ++j) { srcw[j] = srcw[j] / S2; l5 += hj[j] * logf(hj[j] + 1e-10f); }
  float ent = block_sum(l5, scratch);

  *(float4*)&s_lt[sl0]  = *(float4*)ltw;
  *(float4*)&s_src[sl0] = *(float4*)srcw;
  *(float4*)&s_phi[sl0] = make_float4(0.f, 0.f, 0.f, 0.f);
  *(float4*)&s_lse[sl0] = make_float4(0.f, 0.f, 0.f, 0.f);
  if (tid == 0) {    // pads: inert (validated R3..R8)
    #pragma unroll
    for (int p = 0; p < 4; ++p) {
      s_lt[p] = -100.f; s_src[p] = 0.f; s_phi[p] = 0.f; s_lse[p] = 0.f;
      s_lt[KCB+4+p] = -100.f; s_src[KCB+4+p] = 0.f; s_phi[KCB+4+p] = 0.f; s_lse[KCB+4+p] = 0.f;
    }
  }
  __syncthreads();

  float ws[12];
  #pragma unroll
  for (int m = 0; m < 3; ++m) *(float4*)&ws[m*4] = *(float4*)&s_src[i0 + m*4];

  float phi[4] = {0.f, 0.f, 0.f, 0.f};
  float lse[4];
  for (int it = 0; it <= 10; ++it) {
    float wl[12], wp[12];
    #pragma unroll
    for (int m = 0; m < 3; ++m) {
      *(float4*)&wl[m*4] = *(float4*)&s_lt[i0 + m*4];
      *(float4*)&wp[m*4] = *(float4*)&s_phi[i0 + m*4];
    }
    #pragma unroll
    for (int j = 0; j < 4; ++j) {
      float mx = -3.0e38f;
      float vv[5];
      #pragma unroll
      for (int qq = 0; qq < 5; ++qq) {
        int m = j + qq + 2;
        float a = wl[m] + (wp[m] - fabsf((float)(qq - 2))) * 20.0f;
        vv[qq] = a;
        mx = fmaxf(mx, a);
      }
      float ssum = 0.f;
      #pragma unroll
      for (int qq = 0; qq < 5; ++qq) ssum += expf(vv[qq] - mx);
      lse[j] = mx + logf(ssum);
    }
    *(float4*)&s_lse[sl0] = *(float4*)lse;
    __syncthreads();
    if (it == 10) break;

    float we[12];
    #pragma unroll
    for (int m = 0; m < 3; ++m) *(float4*)&we[m*4] = *(float4*)&s_lse[i0 + m*4];
    #pragma unroll
    for (int j = 0; j < 4; ++j) {
      float basej = ltw[j] + phi[j] * 20.0f;
      float cs = 0.f;
      #pragma unroll
      for (int qq = 0; qq < 5; ++qq) {
        int m = j + qq + 2;
        float a = basej - fabsf((float)(qq - 2)) * 20.0f;
        cs += ws[m] * expf(a - we[m]);
      }
      phi[j] += 0.5f * (tgt[j] - cs);
    }
    *(float4*)&s_phi[sl0] = *(float4*)phi;
    __syncthreads();
  }

  float lo = 0.f;
  #pragma unroll
  for (int j = 0; j < 4; ++j) lo += srcw[j] * (-0.05f * lse[j]) + tgt[j] * phi[j];
  float ot = block_sum(lo, scratch);

  if (tid == 0) {
    out[2097152] = 1.25f * (msetot * (1.0f / 2097152.0f)) + ot;
    out[2097153] = expf(-ent);
  }
}

extern "C" void kernel_launch(void* const* d_in, const int* in_sizes, int n_in,
                              void* d_out, int out_size, void* d_ws, size_t ws_size,
                              hipStream_t stream) {
  const float* x  = (const float*)d_in[0];   // [32,64,32,32]
  const float* cb = (const float*)d_in[1];   // [1024,64]
  float* out = (float*)d_out;                // quantized(2097152) | loss | perplexity

  float4* cbf  = (float4*)d_ws;                        // 256 KB fragment-ordered codes
  float*  cnorm = (float*)((char*)d_ws + 262144);      // 4 KB
  int*    hist  = (int*)((char*)d_ws + 266240);        // 4 KB
  float*  msep  = (float*)((char*)d_ws + 270336);      // 2 KB

  k_cvt<<<16, 64, 0, stream>>>(cb, cbf, cnorm, hist);  // hist zeroed here
  k_dist<<<512, 512, 0, stream>>>(x, cb, cbf, cnorm, hist, msep, out);
  k_ot<<<1, 256, 0, stream>>>(hist, msep, out);
}

// Round 2
// 109.031 us; speedup vs baseline: 1.3366x; 1.3366x over previous
//
#include <hip/hip_runtime.h>
#include <math.h>

// Problem constants: B=32, C=D=64, H=W=32
#define NPTS 32768      // B*H*W
#define KCB  1024
#define DIM  64
#define HW   1024
#define CHW  65536

typedef short  bf16x8 __attribute__((ext_vector_type(8)));
typedef float  f32x16 __attribute__((ext_vector_type(16)));

__device__ __forceinline__ unsigned short f2b_rne(float f) {
  unsigned u = __float_as_uint(f);
  unsigned r = 0x7FFFu + ((u >> 16) & 1u);
  return (unsigned short)((u + r) >> 16);
}

__device__ __forceinline__ float block_sum(float v, float* scratch) {
  #pragma unroll
  for (int o = 32; o > 0; o >>= 1) v += __shfl_down(v, o, 64);
  int wid  = threadIdx.x >> 6;
  int lane = threadIdx.x & 63;
  __syncthreads();
  if (lane == 0) scratch[wid] = v;
  __syncthreads();
  float s = 0.f;
  int nw = blockDim.x >> 6;
  for (int w = 0; w < nw; ++w) s += scratch[w];
  return s;
}

// K0: codebook -> fragment-ordered bf16 hi/lo global array + cnorm (exact chain).
// Also zeroes hist (1024 threads cover 1024 bins) -> memset dispatch removed.
__global__ __launch_bounds__(64) void k_cvt(const float* __restrict__ cb,
                                            float4* __restrict__ cbf,
                                            float* __restrict__ cnorm,
                                            int* __restrict__ hist) {
  int c = blockIdx.x * 64 + threadIdx.x;   // 16 blocks x 64 = 1024 codes
  hist[c] = 0;
  const float4* row4 = (const float4*)(cb + c * DIM);
  float4 r[16];
  #pragma unroll
  for (int i = 0; i < 16; ++i) r[i] = row4[i];
  float s = 0.f;
  #pragma unroll
  for (int i = 0; i < 16; ++i) {          // exact f4 fmaf chain (validated rounds)
    s = fmaf(r[i].x, r[i].x, s); s = fmaf(r[i].y, r[i].y, s);
    s = fmaf(r[i].z, r[i].z, s); s = fmaf(r[i].w, r[i].w, s);
  }
  cnorm[c] = s;
  int ch = c >> 6, nt = (c >> 5) & 1, n = c & 31;
  int base = ch * 1024 + nt * 256 + n;
  #pragma unroll
  for (int o = 0; o < 8; ++o) {           // octet o = dims 8o..8o+7
    float f[8] = {r[2*o].x, r[2*o].y, r[2*o].z, r[2*o].w,
                  r[2*o+1].x, r[2*o+1].y, r[2*o+1].z, r[2*o+1].w};
    unsigned hu[4], lu[4];
    #pragma unroll
    for (int j = 0; j < 4; ++j) {
      unsigned short h0 = f2b_rne(f[2*j]),   h1 = f2b_rne(f[2*j+1]);
      float hf0 = __uint_as_float((unsigned)h0 << 16);
      float hf1 = __uint_as_float((unsigned)h1 << 16);
      unsigned short l0 = f2b_rne(f[2*j] - hf0), l1 = f2b_rne(f[2*j+1] - hf1);
      hu[j] = (unsigned)h0 | ((unsigned)h1 << 16);
      lu[j] = (unsigned)l0 | ((unsigned)l1 << 16);
    }
    int pos = base + (o >> 1) * 64 + (o & 1) * 32;   // s = o>>1, u = o&1
    uint4 hv = {hu[0], hu[1], hu[2], hu[3]};
    uint4 lv = {lu[0], lu[1], lu[2], lu[3]};
    cbf[pos]       = *(float4*)&hv;
    cbf[pos + 512] = *(float4*)&lv;
  }
}

// K1: 32x32x16-MFMA distance GEMM + fused fin. 512 blocks x 256 thr x 64 pts.
// ROUND-2 CHANGE: B-fragments are read DIRECTLY from L2-resident cbf (256 KB)
// into registers — no LDS staging of codes, no double-buffer, and ZERO
// barriers in the 16-chunk loop (was 32). Waves are fully independent
// dataflow; a 1-deep register prefetch (fully unrolled, static indices)
// pipelines chunk ch+1's L2 loads under chunk ch's MFMA chain.
// Per-chunk math (A/B frag bits, 12-MFMA chain order, dist formula,
// asc-ch first-min, packed-u64 ties, fin-from-regs) is verbatim from the
// validated kernels -> bit-exact.
__global__ __launch_bounds__(256, 2) void k_dist(const float* __restrict__ x,
                                                 const float* __restrict__ cb,
                                                 const float4* __restrict__ cbf,
                                                 const float* __restrict__ cnorm,
                                                 int* __restrict__ hist,
                                                 float* __restrict__ msep,
                                                 float* __restrict__ out) {
  __shared__ unsigned short lph[64][72], lpl[64][72];  // point bf16 hi/lo rows
  __shared__ float s_cn[KCB];
  __shared__ float s_sx[64], s_part[4][64];
  __shared__ unsigned long long s_pk[64][2];
  __shared__ int   s_bd[64];
  __shared__ float scratch[4];

  int tid = threadIdx.x;
  int t   = blockIdx.x;
  int n0  = t * 64;
  int b   = n0 >> 10;
  int hw0 = n0 & 1023;

  *(float4*)&s_cn[tid * 4] = *(const float4*)(cnorm + tid * 4);

  // point staging + bf16 hi/lo conversion (validated pattern; fx[] keeps the
  // exact x values in registers for the fused fin — no global re-read)
  float fx[16];
  {
    int p = tid & 63, q4 = tid >> 6;
    const float* xb = x + b * CHW + hw0 + p;
    float s = 0.f;
    unsigned short hb[16], lb[16];
    #pragma unroll
    for (int i = 0; i < 16; ++i) {
      int c = q4 * 16 + i;
      float f = xb[c * HW];
      fx[i] = f;
      s = fmaf(f, f, s);
      unsigned short h = f2b_rne(f);
      float hf = __uint_as_float(((unsigned)h) << 16);
      hb[i] = h;
      lb[i] = f2b_rne(f - hf);
    }
    s_part[q4][p] = s;
    #pragma unroll
    for (int j = 0; j < 8; ++j) {
      *(unsigned*)&lph[p][q4 * 16 + 2 * j] = (unsigned)hb[2*j] | ((unsigned)hb[2*j+1] << 16);
      *(unsigned*)&lpl[p][q4 * 16 + 2 * j] = (unsigned)lb[2*j] | ((unsigned)lb[2*j+1] << 16);
    }
  }
  __syncthreads();
  if (tid < 64)
    s_sx[tid] = ((s_part[0][tid] + s_part[1][tid]) + s_part[2][tid]) + s_part[3][tid];
  __syncthreads();

  int w = tid >> 6, l = tid & 63;
  int wm = w >> 1, wn = w & 1;
  int u = l >> 5, n = l & 31;

  // A-frags: lane holds A[m=n][k=u*8+j] for k-step s -> octet (2s+u) of point row
  bf16x8 ah[4], al[4];
  {
    int pt = wm * 32 + n;
    #pragma unroll
    for (int s = 0; s < 4; ++s) {
      ah[s] = *(const bf16x8*)&lph[pt][(2 * s + u) * 8];
      al[s] = *(const bf16x8*)&lpl[pt][(2 * s + u) * 8];
    }
  }
  // C/D 32x32 layout: col=lane&31, row=(reg&3)+8*(reg>>2)+4*(lane>>5)  [m74/m101]
  float sxr[16];
  #pragma unroll
  for (int r = 0; r < 16; ++r)
    sxr[r] = s_sx[wm * 32 + (r & 3) + 8 * (r >> 2) + 4 * u];

  float best[16]; int bidx[16];
  #pragma unroll
  for (int r = 0; r < 16; ++r) { best[r] = 3.4e38f; bidx[r] = 0; }

  // B-frag global base: 16B units; chunk ch at gb + ch*1024;
  // hi frag (s) at bofs + s*64, lo at +512. Same bits as the old LDS copy.
  int bofs = wn * 256 + u * 32 + n;
  const bf16x8* gb = (const bf16x8*)cbf;

  // prefetch chunk 0 B-frags into registers (issued after last barrier:
  // nothing downstream drains vmcnt until first use)
  bf16x8 cbh[4], cbl[4], nbh[4], nbl[4];
  #pragma unroll
  for (int s = 0; s < 4; ++s) {
    cbh[s] = gb[bofs + s * 64];
    cbl[s] = gb[bofs + s * 64 + 512];
  }

  #pragma unroll
  for (int ch = 0; ch < 16; ++ch) {
    if (ch < 15) {                      // issue next chunk's loads early
      const bf16x8* gn = gb + (ch + 1) * 1024;
      #pragma unroll
      for (int s = 0; s < 4; ++s) {
        nbh[s] = gn[bofs + s * 64];
        nbl[s] = gn[bofs + s * 64 + 512];
      }
    }
    f32x16 acc;
    #pragma unroll
    for (int r = 0; r < 16; ++r) acc[r] = 0.f;
    #pragma unroll
    for (int s = 0; s < 4; ++s) {       // EXACT 12-MFMA chain order (validated)
      acc = __builtin_amdgcn_mfma_f32_32x32x16_bf16(ah[s], cbh[s], acc, 0, 0, 0);
      acc = __builtin_amdgcn_mfma_f32_32x32x16_bf16(ah[s], cbl[s], acc, 0, 0, 0);
      acc = __builtin_amdgcn_mfma_f32_32x32x16_bf16(al[s], cbh[s], acc, 0, 0, 0);
    }
    int   kk  = ch * 64 + wn * 32 + n;
    float cnv = s_cn[kk];
    #pragma unroll
    for (int r = 0; r < 16; ++r) {
      // reference fp32 rounding shape: (||x||^2 + ||c||^2) - 2*x.c
      float dist = (sxr[r] + cnv) - 2.0f * acc[r];
      if (dist < best[r]) { best[r] = dist; bidx[r] = kk; }  // ch asc -> first-min
    }
    if (ch < 15) {                      // reg renames (free under full unroll)
      #pragma unroll
      for (int s = 0; s < 4; ++s) { cbh[s] = nbh[s]; cbl[s] = nbl[s]; }
    }
  }

  // cross-lane argmin within each 32-lane half (cols of the 32x32 tile)
  #pragma unroll
  for (int r = 0; r < 16; ++r) {
    unsigned long long p =
        ((unsigned long long)__float_as_uint(best[r]) << 32) | (unsigned)bidx[r];
    #pragma unroll
    for (int m = 1; m < 32; m <<= 1) {
      unsigned long long o = __shfl_xor(p, m, 64);
      p = (o < p) ? o : p;
    }
    if (n == 0)
      s_pk[wm * 32 + (r & 3) + 8 * (r >> 2) + 4 * u][wn] = p;
  }
  __syncthreads();
  if (tid < 64) {
    unsigned long long a = s_pk[tid][0], c2 = s_pk[tid][1];
    unsigned long long mn = (c2 < a) ? c2 : a;   // tie -> lower idx (half0 < half1)
    int bd = (int)(mn & 0xffffffffull);
    s_bd[tid] = bd;
    atomicAdd(&hist[bd], 1);
  }
  __syncthreads();

  // fused fin: gather code row, straight-through write (ref rounding), mse.
  // x comes from registers (fx) — exact same per-thread se chain as validated.
  float se = 0.f;
  {
    int p = tid & 63, cg = tid >> 6;
    int bd = s_bd[p];
    const float* crow = cb + bd * DIM;
    float* ob = out + b * CHW + hw0 + p;
    #pragma unroll 4
    for (int i = 0; i < 16; ++i) {
      int c = cg * 16 + i;
      float xv   = fx[i];              // exact x (kept in regs from staging)
      float diff = crow[c] - xv;       // nq - x
      se += diff * diff;               // (clean_q - flat)^2 == commit mse
      ob[c * HW] = xv + diff;          // x + stop_grad(nq - x)
    }
  }
  float tot = block_sum(se, scratch);
  if (tid == 0) msep[t] = tot;         // plain store: no atomics, no pre-zero
}

// K2: prep + banded OT dual ascent + scalars (R8 structure, unchanged).
__global__ __launch_bounds__(256) void k_ot(const int* __restrict__ hist,
                                            const float* __restrict__ msep,
                                            float* __restrict__ out) {
  __shared__ __align__(16) float s_lt[KCB + 8], s_src[KCB + 8],
                                 s_phi[KCB + 8], s_lse[KCB + 8];
  __shared__ float scratch[4];
  int tid = threadIdx.x;
  int i0  = tid * 4;
  int sl0 = i0 + 4;

  float msetot = block_sum(msep[tid] + msep[tid + 256], scratch);

  int4 hi4 = *(const int4*)(hist + i0);
  int  hi[4] = {hi4.x, hi4.y, hi4.z, hi4.w};
  float tj[4], hj[4];
  #pragma unroll
  for (int j = 0; j < 4; ++j) {
    float fi = (float)(i0 + j);
    float zz = (fi - 511.5f) / (1024.0f / 6.0f);
    tj[j] = expf(-0.5f * zz * zz);
    hj[j] = (float)hi[j] * (1.0f / 32768.0f);
  }
  float St = block_sum(tj[0] + tj[1] + tj[2] + tj[3], scratch);
  float tgt[4], ltw[4];
  float l2 = 0.f;
  #pragma unroll
  for (int j = 0; j < 4; ++j) { tgt[j] = fmaxf(tj[j] / fmaxf(St, 1e-12f), 1e-12f); l2 += tgt[j]; }
  float St2 = block_sum(l2, scratch);
  #pragma unroll
  for (int j = 0; j < 4; ++j) { tgt[j] = tgt[j] / St2; ltw[j] = logf(fmaxf(tgt[j], 1e-12f)); }

  float m1[4], srcw[4];
  float l3 = 0.f;
  #pragma unroll
  for (int j = 0; j < 4; ++j) { m1[j] = fmaxf(hj[j], 1e-12f); l3 += m1[j]; }
  float S1 = block_sum(l3, scratch);
  float l4 = 0.f;
  #pragma unroll
  for (int j = 0; j < 4; ++j) { srcw[j] = fmaxf(m1[j] / S1, 1e-12f); l4 += srcw[j]; }
  float S2 = block_sum(l4, scratch);
  float l5 = 0.f;
  #pragma unroll
  for (int j = 0; j < 4; ++j) { srcw[j] = srcw[j] / S2; l5 += hj[j] * logf(hj[j] + 1e-10f); }
  float ent = block_sum(l5, scratch);

  *(float4*)&s_lt[sl0]  = *(float4*)ltw;
  *(float4*)&s_src[sl0] = *(float4*)srcw;
  *(float4*)&s_phi[sl0] = make_float4(0.f, 0.f, 0.f, 0.f);
  *(float4*)&s_lse[sl0] = make_float4(0.f, 0.f, 0.f, 0.f);
  if (tid == 0) {    // pads: inert (validated R3..R8)
    #pragma unroll
    for (int p = 0; p < 4; ++p) {
      s_lt[p] = -100.f; s_src[p] = 0.f; s_phi[p] = 0.f; s_lse[p] = 0.f;
      s_lt[KCB+4+p] = -100.f; s_src[KCB+4+p] = 0.f; s_phi[KCB+4+p] = 0.f; s_lse[KCB+4+p] = 0.f;
    }
  }
  __syncthreads();

  float ws[12];
  #pragma unroll
  for (int m = 0; m < 3; ++m) *(float4*)&ws[m*4] = *(float4*)&s_src[i0 + m*4];

  float phi[4] = {0.f, 0.f, 0.f, 0.f};
  float lse[4];
  for (int it = 0; it <= 10; ++it) {
    float wl[12], wp[12];
    #pragma unroll
    for (int m = 0; m < 3; ++m) {
      *(float4*)&wl[m*4] = *(float4*)&s_lt[i0 + m*4];
      *(float4*)&wp[m*4] = *(float4*)&s_phi[i0 + m*4];
    }
    #pragma unroll
    for (int j = 0; j < 4; ++j) {
      float mx = -3.0e38f;
      float vv[5];
      #pragma unroll
      for (int qq = 0; qq < 5; ++qq) {
        int m = j + qq + 2;
        float a = wl[m] + (wp[m] - fabsf((float)(qq - 2))) * 20.0f;
        vv[qq] = a;
        mx = fmaxf(mx, a);
      }
      float ssum = 0.f;
      #pragma unroll
      for (int qq = 0; qq < 5; ++qq) ssum += expf(vv[qq] - mx);
      lse[j] = mx + logf(ssum);
    }
    *(float4*)&s_lse[sl0] = *(float4*)lse;
    __syncthreads();
    if (it == 10) break;

    float we[12];
    #pragma unroll
    for (int m = 0; m < 3; ++m) *(float4*)&we[m*4] = *(float4*)&s_lse[i0 + m*4];
    #pragma unroll
    for (int j = 0; j < 4; ++j) {
      float basej = ltw[j] + phi[j] * 20.0f;
      float cs = 0.f;
      #pragma unroll
      for (int qq = 0; qq < 5; ++qq) {
        int m = j + qq + 2;
        float a = basej - fabsf((float)(qq - 2)) * 20.0f;
        cs += ws[m] * expf(a - we[m]);
      }
      phi[j] += 0.5f * (tgt[j] - cs);
    }
    *(float4*)&s_phi[sl0] = *(float4*)phi;
    __syncthreads();
  }

  float lo = 0.f;
  #pragma unroll
  for (int j = 0; j < 4; ++j) lo += srcw[j] * (-0.05f * lse[j]) + tgt[j] * phi[j];
  float ot = block_sum(lo, scratch);

  if (tid == 0) {
    out[2097152] = 1.25f * (msetot * (1.0f / 2097152.0f)) + ot;
    out[2097153] = expf(-ent);
  }
}

extern "C" void kernel_launch(void* const* d_in, const int* in_sizes, int n_in,
                              void* d_out, int out_size, void* d_ws, size_t ws_size,
                              hipStream_t stream) {
  const float* x  = (const float*)d_in[0];   // [32,64,32,32]
  const float* cb = (const float*)d_in[1];   // [1024,64]
  float* out = (float*)d_out;                // quantized(2097152) | loss | perplexity

  float4* cbf  = (float4*)d_ws;                        // 256 KB fragment-ordered codes
  float*  cnorm = (float*)((char*)d_ws + 262144);      // 4 KB
  int*    hist  = (int*)((char*)d_ws + 266240);        // 4 KB
  float*  msep  = (float*)((char*)d_ws + 270336);      // 2 KB

  k_cvt<<<16, 64, 0, stream>>>(cb, cbf, cnorm, hist);  // hist zeroed here
  k_dist<<<512, 256, 0, stream>>>(x, cb, cbf, cnorm, hist, msep, out);
  k_ot<<<1, 256, 0, stream>>>(hist, msep, out);
}